// Round 8
// baseline (394.676 us; speedup 1.0000x reference)
//
#include <hip/hip_runtime.h>
#include <hip/hip_bf16.h>

typedef __attribute__((ext_vector_type(8))) short short8;
typedef __attribute__((ext_vector_type(4))) short s16x4;
typedef __attribute__((ext_vector_type(4))) float f32x4;
typedef unsigned short u16;

// round-to-nearest-even fp32 -> bf16
__device__ inline u16 f2bf(float f) {
    union { float f; unsigned u; } x{f};
    unsigned r = (x.u + 0x7fff + ((x.u >> 16) & 1)) >> 16;
    return (u16)r;
}

// pack two fp32 -> packed bf16 pair (round-half-up via +0x8000, then v_perm)
__device__ inline unsigned pkbf(float hi, float lo) {
    unsigned a = __builtin_bit_cast(unsigned, hi) + 0x8000u;
    unsigned b = __builtin_bit_cast(unsigned, lo) + 0x8000u;
    return __builtin_amdgcn_perm(a, b, 0x07060302u);
}

// async 16B global -> LDS (wave-uniform base + lane*16 layout)
__device__ inline void glds16(const u16* g, u16* l) {
    __builtin_amdgcn_global_load_lds(
        (const __attribute__((address_space(1))) void*)g,
        (__attribute__((address_space(3))) void*)l, 16, 0, 0);
}

// ---------------- fused prep: cvt x -> bf16 | transpose w_in | w_out --------
__global__ __launch_bounds__(256) void prep(const float* __restrict__ x,
                                            const float* __restrict__ w_in,
                                            const float* __restrict__ w_out,
                                            u16* __restrict__ Xb,
                                            u16* __restrict__ WtIn,
                                            u16* __restrict__ WtOut) {
    __shared__ float tile[32][33];
    int bx = blockIdx.x, tid = threadIdx.x;
    if (bx < 4096) {
        int i = (bx * 256 + tid) * 4;
        float4 v = *(const float4*)&x[i];
        uint2 o;
        o.x = (unsigned)f2bf(v.x) | ((unsigned)f2bf(v.y) << 16);
        o.y = (unsigned)f2bf(v.z) | ((unsigned)f2bf(v.w) << 16);
        *(uint2*)&Xb[i] = o;
        return;
    }
    const float* W; u16* Wt; int K, N, n0, k0;
    if (bx < 7168) {
        int b2 = bx - 4096;                 // w_in: K=1024, N=3072
        W = w_in; Wt = WtIn; K = 1024; N = 3072;
        n0 = (b2 % 96) * 32; k0 = (b2 / 96) * 32;
    } else {
        int b3 = bx - 7168;                 // w_out: K=1024, N=1024
        W = w_out; Wt = WtOut; K = 1024; N = 1024;
        n0 = (b3 & 31) * 32; k0 = (b3 >> 5) * 32;
    }
    int tx = tid & 31, ty = tid >> 5;
    for (int i = 0; i < 32; i += 8)
        tile[ty + i][tx] = W[(size_t)(k0 + ty + i) * N + n0 + tx];
    __syncthreads();
    for (int i = 0; i < 32; i += 8)
        Wt[(size_t)(n0 + ty + i) * K + k0 + tx] = f2bf(tile[tx][ty + i]);
}

// ---------------- transpose V slice of qkv -> Vt[b,h,dh,S] bf16 -------------
__global__ __launch_bounds__(256) void transpose_v(const u16* __restrict__ qkv,
                                                   u16* __restrict__ VT) {
    __shared__ u16 t[32][33];
    int s0 = blockIdx.x * 32, d0 = blockIdx.y * 32, bh = blockIdx.z;
    int b = bh >> 4, h = bh & 15;
    int tx = threadIdx.x, ty = threadIdx.y; // block (32,8)
    const u16* Vp = qkv + (size_t)(b * 2048) * 3072 + 2048 + h * 64;
    for (int i = 0; i < 32; i += 8)
        t[ty + i][tx] = Vp[(size_t)(s0 + ty + i) * 3072 + d0 + tx];
    __syncthreads();
    u16* Vr = VT + (size_t)bh * 64 * 2048;
    for (int i = 0; i < 32; i += 8)
        Vr[(size_t)(d0 + ty + i) * 2048 + s0 + tx] = t[tx][ty + i];
}

// ---------------- GEMM: C[M][N] = A[M][K] @ Bt[N][K]^T + bias ---------------
#define BM 128
#define BN 128
#define BK 64
__global__ __launch_bounds__(256) void gemm_bt(const u16* __restrict__ A,
                                               const u16* __restrict__ Bt,
                                               const float* __restrict__ bias,
                                               void* __restrict__ C,
                                               int M, int N, int K, int c_is_f32,
                                               int qcols, float qscale) {
    __shared__ u16 smem[2 * BM * BK + 2048];
    u16* As = smem;
    u16* Bs = smem + BM * BK;

    int tid = threadIdx.x;
    int wave = tid >> 6, lane = tid & 63;
    int quad = lane >> 4, l16 = lane & 15;
    int wm = (wave >> 1) * 64, wn = (wave & 1) * 64;

    int nm = M / BM, nn = N / BN;
    const int GM = 8;
    int per_group = GM * nn;
    int group = blockIdx.x / per_group;
    int rem = blockIdx.x % per_group;
    int first_m = group * GM;
    int gsz = (nm - first_m < GM) ? (nm - first_m) : GM;
    int m0 = (first_m + rem % gsz) * BM;
    int n0 = (rem / gsz) * BN;

    f32x4 acc[4][4] = {};

    for (int k0 = 0; k0 < K; k0 += BK) {
        __syncthreads();
        for (int i = 0; i < 4; i++) {
            int c = tid + i * 256;
            int r = c >> 3, cc = c & 7;
            int gsrc = (cc ^ (r & 7)) * 8;          // XOR swizzle
            glds16(&A[(size_t)(m0 + r) * K + k0 + gsrc], As + c * 8);
            glds16(&Bt[(size_t)(n0 + r) * K + k0 + gsrc], Bs + c * 8);
        }
        __syncthreads();
        for (int ks = 0; ks < 2; ks++) {
            short8 af[4], bf[4];
            for (int i = 0; i < 4; i++) {
                int row = wm + i * 16 + l16;
                int slot = (ks * 4 + quad) ^ (row & 7);
                af[i] = *(short8*)&As[row * BK + slot * 8];
            }
            for (int j = 0; j < 4; j++) {
                int row = wn + j * 16 + l16;
                int slot = (ks * 4 + quad) ^ (row & 7);
                bf[j] = *(short8*)&Bs[row * BK + slot * 8];
            }
            for (int i = 0; i < 4; i++)
                for (int j = 0; j < 4; j++)
                    acc[i][j] = __builtin_amdgcn_mfma_f32_16x16x32_bf16(
                        af[i], bf[j], acc[i][j], 0, 0, 0);
        }
    }

    if (c_is_f32) {
        for (int i = 0; i < 4; i++)
            for (int j = 0; j < 4; j++) {
                int col = n0 + wn + j * 16 + l16;
                float bv = bias ? bias[col] : 0.f;
                for (int r = 0; r < 4; r++) {
                    int row = m0 + wm + i * 16 + quad * 4 + r;
                    ((float*)C)[(size_t)row * N + col] = acc[i][j][r] + bv;
                }
            }
    } else {
        __syncthreads();
        u16 (*buf)[136] = (u16(*)[136])smem;
        for (int i = 0; i < 4; i++)
            for (int j = 0; j < 4; j++) {
                int col = wn + j * 16 + l16;
                float bv = bias ? bias[n0 + col] : 0.f;
                float scl = (n0 + col < qcols) ? qscale : 1.f;
                for (int r = 0; r < 4; r++)
                    buf[wm + i * 16 + quad * 4 + r][col] =
                        f2bf((acc[i][j][r] + bv) * scl);
            }
        __syncthreads();
        u16* Cb = (u16*)C;
        for (int it = 0; it < 8; it++) {
            int c = tid + it * 256;
            int row = c >> 4, k8 = c & 15;
            uint4 v = *(uint4*)&buf[row][k8 * 8];
            *(uint4*)&Cb[(size_t)(m0 + row) * N + n0 + k8 * 8] = v;
        }
    }
}

// ---------------- flash attention (causal), paired 64-row Q-tiles -----------
// 512 blocks x 256 threads (4 waves x 16 q-rows = 64 rows/block; 2 blocks/CU
// for cross-block latency hiding). Block p pairs qt'=31-p (32-p tiles) with
// qt'=p (p+1 tiles): exactly 33 k-iterations per block. S^T trick keeps P in
// registers (A-layout of 16x16x16). Q pre-scaled by 0.125*log2e in gemm1.
__global__ __launch_bounds__(256) void attn_kernel(const u16* __restrict__ qkv,
                                                   const u16* __restrict__ VT,
                                                   u16* __restrict__ out) {
    const int S = 2048, D = 1024, stride = 3072;
    int idx = blockIdx.x;                 // 512 blocks
    int p = idx >> 5, bh = idx & 31;      // p in 0..15
    int qtb[2] = {31 - p, p};             // 64-row tiles; phase 0 large
    int b = bh >> 4, h = bh & 15;
    int tid = threadIdx.x;
    int wave = tid >> 6, lane = tid & 63;
    int quad = lane >> 4, l16 = lane & 15;

    __shared__ u16 Klds[2][64 * 64];      // slot (r,cc) holds chunk (r, cc^(r&7))
    __shared__ u16 Vlds[2][64 * 64];
    __shared__ u16 Obuf[4][16][72];       // per-wave output repack

    const u16* Qp = qkv + (size_t)(b * S) * stride + h * 64;
    const u16* Kp = Qp + D;
    const u16* Vtp = VT + (size_t)bh * 64 * S;

    short8 qf[2][2];                      // [phase][k-half]
    for (int ph = 0; ph < 2; ph++) {
        int qrow = qtb[ph] * 64 + wave * 16 + l16;
        qf[ph][0] = *(const short8*)&Qp[(size_t)qrow * stride + quad * 8];
        qf[ph][1] = *(const short8*)&Qp[(size_t)qrow * stride + 32 + quad * 8];
    }

    int nt0 = qtb[0] + 1;
    int total = nt0 + qtb[1] + 1;         // always 33

    auto stage = [&](int kt, int bsel) {
        for (int i = 0; i < 2; i++) {
            int c = tid + i * 256;        // 512 chunks of 16B each for K and V
            int r = c >> 3, cc = c & 7;
            int gsrc = (cc ^ (r & 7)) * 8;
            glds16(&Kp[(size_t)(kt * 64 + r) * stride + gsrc], &Klds[bsel][c * 8]);
            glds16(&Vtp[(size_t)r * S + kt * 64 + gsrc], &Vlds[bsel][c * 8]);
        }
    };

    stage(0, 0);

    f32x4 O[4] = {};
    float lsum = 0.f;

    for (int it = 0; it < total; it++) {
        int ph = (it >= nt0) ? 1 : 0;
        int kt = ph ? it - nt0 : it;
        int qt = qtb[ph];
        int cur = it & 1;
        __syncthreads();                  // drains DMA for this tile
        if (it + 1 < total) {
            int it2 = it + 1;
            int k2 = (it2 >= nt0) ? it2 - nt0 : it2;
            stage(k2, cur ^ 1);
        }

        // K fragments (A-operand): rows = seq
        short8 kf[4][2];
        for (int nb = 0; nb < 4; nb++) {
            int r = nb * 16 + l16;
            kf[nb][0] = *(short8*)&Klds[cur][r * 64 + ((0 + quad) ^ (r & 7)) * 8];
            kf[nb][1] = *(short8*)&Klds[cur][r * 64 + ((4 + quad) ^ (r & 7)) * 8];
        }
        // S^T[k][q]: lane q=l16, k=nb*16+quad*4+r (pre-scaled Q)
        f32x4 st[4];
        for (int nb = 0; nb < 4; nb++) {
            f32x4 t = {};
            t = __builtin_amdgcn_mfma_f32_16x16x32_bf16(kf[nb][0], qf[ph][0], t, 0, 0, 0);
            t = __builtin_amdgcn_mfma_f32_16x16x32_bf16(kf[nb][1], qf[ph][1], t, 0, 0, 0);
            st[nb] = t;
        }

        if (kt == qt) {                   // causal boundary tile
            int qabs = qt * 64 + wave * 16 + l16;
            for (int nb = 0; nb < 4; nb++) {
                int kb = kt * 64 + nb * 16 + quad * 4;
                for (int r = 0; r < 4; r++) {
                    float e = __builtin_amdgcn_exp2f(st[nb][r]);
                    st[nb][r] = (kb + r <= qabs) ? e : 0.f;
                }
            }
        } else {
            for (int nb = 0; nb < 4; nb++)
                for (int r = 0; r < 4; r++)
                    st[nb][r] = __builtin_amdgcn_exp2f(st[nb][r]);
        }

        // partial row sums + pack P to bf16 A-frags (v_perm, round-half-up)
        s16x4 pf[4];
        for (int nb = 0; nb < 4; nb++) {
            lsum += (st[nb][0] + st[nb][1]) + (st[nb][2] + st[nb][3]);
            uint2 pk;
            pk.x = pkbf(st[nb][1], st[nb][0]);
            pk.y = pkbf(st[nb][3], st[nb][2]);
            pf[nb] = __builtin_bit_cast(s16x4, pk);
        }

        // O[q][d] += P @ V via 16x16x16 (k=16 seq chunks)
        for (int db = 0; db < 4; db++) {
            int rr = db * 16 + l16;
            for (int kc = 0; kc < 4; kc++) {
                int g = kc * 2 + (quad >> 1);
                int slot = g ^ (rr & 7);
                s16x4 vf = *(s16x4*)&Vlds[cur][rr * 64 + slot * 8 + (quad & 1) * 4];
                O[db] = __builtin_amdgcn_mfma_f32_16x16x16bf16_1k(
                    pf[kc], vf, O[db], 0, 0, 0);
            }
        }

        // phase epilogue (after the phase's last tile)
        if (it == nt0 - 1 || it == total - 1) {
            float v = lsum;
            v += __shfl_xor(v, 16);
            v += __shfl_xor(v, 32);       // full row sum at lane q=l16
            float rinv[4];
            for (int r = 0; r < 4; r++)
                rinv[r] = 1.f / __shfl(v, (lane & 48) | (quad * 4 + r));
            for (int db = 0; db < 4; db++)
                for (int r = 0; r < 4; r++)
                    Obuf[wave][quad * 4 + r][db * 16 + l16] =
                        f2bf(O[db][r] * rinv[r]);
            __asm__ volatile("s_waitcnt lgkmcnt(0)" ::: "memory");
            for (int i = 0; i < 2; i++) {
                int c = i * 64 + lane;
                int row = c >> 3, cc = c & 7;
                uint4 vv = *(uint4*)&Obuf[wave][row][cc * 8];
                int grow = qt * 64 + wave * 16 + row;
                *(uint4*)&out[(size_t)(b * S + grow) * D + h * 64 + cc * 8] = vv;
            }
            for (int db = 0; db < 4; db++) O[db] = (f32x4){0.f, 0.f, 0.f, 0.f};
            lsum = 0.f;
        }
    }
}

// ---------------------------------------------------------------------------
extern "C" void kernel_launch(void* const* d_in, const int* in_sizes, int n_in,
                              void* d_out, int out_size, void* d_ws, size_t ws_size,
                              hipStream_t stream) {
    const float* x     = (const float*)d_in[0];
    const float* w_in  = (const float*)d_in[1];
    const float* b_in  = (const float*)d_in[2];
    const float* w_out = (const float*)d_in[3];
    const float* b_out = (const float*)d_in[4];

    const int Bsz = 2, S = 2048, D = 1024, H = 16;
    const int M = Bsz * S;
    const int N1 = 3 * D;
    const float sc = 0.125f * 1.44269504f;  // 1/sqrt(64) * log2(e)

    u16* ws    = (u16*)d_ws;
    u16* Xb    = ws;
    u16* WtIn  = Xb + (size_t)M * D;
    u16* WtOut = WtIn + (size_t)N1 * D;
    u16* qkvb  = WtOut + (size_t)D * D;
    u16* attnb = qkvb + (size_t)M * N1;
    u16* Vt    = Xb;                       // alias: Xb dead once gemm1 ran

    prep<<<8192, 256, 0, stream>>>(x, w_in, w_out, Xb, WtIn, WtOut);
    gemm_bt<<<(M / BM) * (N1 / BN), 256, 0, stream>>>(Xb, WtIn, b_in, qkvb,
                                                      M, N1, D, 0, D, sc);
    transpose_v<<<dim3(S / 32, 2, Bsz * H), dim3(32, 8), 0, stream>>>(qkvb, Vt);
    attn_kernel<<<512, 256, 0, stream>>>(qkvb, Vt, attnb);
    gemm_bt<<<(M / BM) * (D / BN), 256, 0, stream>>>(attnb, WtOut, b_out, d_out,
                                                     M, D, D, 1, 0, 1.f);
}

// Round 9
// 208.369 us; speedup vs baseline: 1.8941x; 1.8941x over previous
//
#include <hip/hip_runtime.h>
#include <hip/hip_bf16.h>

typedef __attribute__((ext_vector_type(8))) short short8;
typedef __attribute__((ext_vector_type(4))) short s16x4;
typedef __attribute__((ext_vector_type(4))) float f32x4;
typedef unsigned short u16;

// round-to-nearest-even fp32 -> bf16
__device__ inline u16 f2bf(float f) {
    union { float f; unsigned u; } x{f};
    unsigned r = (x.u + 0x7fff + ((x.u >> 16) & 1)) >> 16;
    return (u16)r;
}

// pack two fp32 -> packed bf16 pair (round-half-up via +0x8000, then v_perm)
__device__ inline unsigned pkbf(float hi, float lo) {
    unsigned a = __builtin_bit_cast(unsigned, hi) + 0x8000u;
    unsigned b = __builtin_bit_cast(unsigned, lo) + 0x8000u;
    return __builtin_amdgcn_perm(a, b, 0x07060302u);
}

// async 16B global -> LDS (wave-uniform base + lane*16 layout)
__device__ inline void glds16(const u16* g, u16* l) {
    __builtin_amdgcn_global_load_lds(
        (const __attribute__((address_space(1))) void*)g,
        (__attribute__((address_space(3))) void*)l, 16, 0, 0);
}

// ---------------- fused prep: cvt x -> bf16 | transpose w_in | w_out --------
__global__ __launch_bounds__(256) void prep(const float* __restrict__ x,
                                            const float* __restrict__ w_in,
                                            const float* __restrict__ w_out,
                                            u16* __restrict__ Xb,
                                            u16* __restrict__ WtIn,
                                            u16* __restrict__ WtOut) {
    __shared__ float tile[32][33];
    int bx = blockIdx.x, tid = threadIdx.x;
    if (bx < 4096) {
        int i = (bx * 256 + tid) * 4;
        float4 v = *(const float4*)&x[i];
        uint2 o;
        o.x = (unsigned)f2bf(v.x) | ((unsigned)f2bf(v.y) << 16);
        o.y = (unsigned)f2bf(v.z) | ((unsigned)f2bf(v.w) << 16);
        *(uint2*)&Xb[i] = o;
        return;
    }
    const float* W; u16* Wt; int K, N, n0, k0;
    if (bx < 7168) {
        int b2 = bx - 4096;                 // w_in: K=1024, N=3072
        W = w_in; Wt = WtIn; K = 1024; N = 3072;
        n0 = (b2 % 96) * 32; k0 = (b2 / 96) * 32;
    } else {
        int b3 = bx - 7168;                 // w_out: K=1024, N=1024
        W = w_out; Wt = WtOut; K = 1024; N = 1024;
        n0 = (b3 & 31) * 32; k0 = (b3 >> 5) * 32;
    }
    int tx = tid & 31, ty = tid >> 5;
    for (int i = 0; i < 32; i += 8)
        tile[ty + i][tx] = W[(size_t)(k0 + ty + i) * N + n0 + tx];
    __syncthreads();
    for (int i = 0; i < 32; i += 8)
        Wt[(size_t)(n0 + ty + i) * K + k0 + tx] = f2bf(tile[tx][ty + i]);
}

// ---------------- GEMM: C[M][N] = A[M][K] @ Bt[N][K]^T + bias ---------------
// global_load_lds staging; XOR-swizzled LDS. bf16 epilogue scales cols<qcols
// by qscale (folds softmax scale into Q). If vt_out != null, tiles with
// n0 >= 2048 (the V region of qkv) are stored TRANSPOSED to vt_out[b,h,d,s]
// instead of to C (fuses the V transpose; qkv's V region is never written).
#define BM 128
#define BN 128
#define BK 64
__global__ __launch_bounds__(256) void gemm_bt(const u16* __restrict__ A,
                                               const u16* __restrict__ Bt,
                                               const float* __restrict__ bias,
                                               void* __restrict__ C,
                                               int M, int N, int K, int c_is_f32,
                                               int qcols, float qscale,
                                               u16* __restrict__ vt_out) {
    __shared__ u16 smem[2 * BM * BK + 2048];
    u16* As = smem;
    u16* Bs = smem + BM * BK;

    int tid = threadIdx.x;
    int wave = tid >> 6, lane = tid & 63;
    int quad = lane >> 4, l16 = lane & 15;
    int wm = (wave >> 1) * 64, wn = (wave & 1) * 64;

    int nm = M / BM, nn = N / BN;
    const int GM = 8;
    int per_group = GM * nn;
    int group = blockIdx.x / per_group;
    int rem = blockIdx.x % per_group;
    int first_m = group * GM;
    int gsz = (nm - first_m < GM) ? (nm - first_m) : GM;
    int m0 = (first_m + rem % gsz) * BM;
    int n0 = (rem / gsz) * BN;

    f32x4 acc[4][4] = {};

    for (int k0 = 0; k0 < K; k0 += BK) {
        __syncthreads();
        for (int i = 0; i < 4; i++) {
            int c = tid + i * 256;
            int r = c >> 3, cc = c & 7;
            int gsrc = (cc ^ (r & 7)) * 8;          // XOR swizzle
            glds16(&A[(size_t)(m0 + r) * K + k0 + gsrc], As + c * 8);
            glds16(&Bt[(size_t)(n0 + r) * K + k0 + gsrc], Bs + c * 8);
        }
        __syncthreads();
        for (int ks = 0; ks < 2; ks++) {
            short8 af[4], bf[4];
            for (int i = 0; i < 4; i++) {
                int row = wm + i * 16 + l16;
                int slot = (ks * 4 + quad) ^ (row & 7);
                af[i] = *(short8*)&As[row * BK + slot * 8];
            }
            for (int j = 0; j < 4; j++) {
                int row = wn + j * 16 + l16;
                int slot = (ks * 4 + quad) ^ (row & 7);
                bf[j] = *(short8*)&Bs[row * BK + slot * 8];
            }
            for (int i = 0; i < 4; i++)
                for (int j = 0; j < 4; j++)
                    acc[i][j] = __builtin_amdgcn_mfma_f32_16x16x32_bf16(
                        af[i], bf[j], acc[i][j], 0, 0, 0);
        }
    }

    if (c_is_f32) {
        for (int i = 0; i < 4; i++)
            for (int j = 0; j < 4; j++) {
                int col = n0 + wn + j * 16 + l16;
                float bv = bias ? bias[col] : 0.f;
                for (int r = 0; r < 4; r++) {
                    int row = m0 + wm + i * 16 + quad * 4 + r;
                    ((float*)C)[(size_t)row * N + col] = acc[i][j][r] + bv;
                }
            }
    } else if (vt_out && n0 >= 2048) {
        // V tile: store transposed to vt_out[b*16+h][d][s]
        __syncthreads();
        u16 (*buf_t)[136] = (u16(*)[136])smem;  // [col 0..127][row 0..127]
        for (int i = 0; i < 4; i++)
            for (int j = 0; j < 4; j++) {
                int col = wn + j * 16 + l16;
                float bv = bias[n0 + col];
                for (int r = 0; r < 4; r++)
                    buf_t[col][wm + i * 16 + quad * 4 + r] =
                        f2bf(acc[i][j][r] + bv);
            }
        __syncthreads();
        int col = tid >> 1, half = tid & 1;        // 128 cols x 2 halves
        int h = ((n0 - 2048) >> 6) + (col >> 6);
        int d = col & 63;
        int bb = m0 >> 11;
        int s0r = (m0 & 2047) + half * 64;
        u16* dst = vt_out + ((size_t)(bb * 16 + h) * 64 + d) * 2048 + s0r;
        for (int k = 0; k < 8; k++) {
            uint4 v = *(uint4*)&buf_t[col][half * 64 + k * 8];
            *(uint4*)&dst[k * 8] = v;
        }
    } else {
        __syncthreads();
        u16 (*buf)[136] = (u16(*)[136])smem;
        for (int i = 0; i < 4; i++)
            for (int j = 0; j < 4; j++) {
                int col = wn + j * 16 + l16;
                float bv = bias ? bias[n0 + col] : 0.f;
                float scl = (n0 + col < qcols) ? qscale : 1.f;
                for (int r = 0; r < 4; r++)
                    buf[wm + i * 16 + quad * 4 + r][col] =
                        f2bf((acc[i][j][r] + bv) * scl);
            }
        __syncthreads();
        u16* Cb = (u16*)C;
        for (int it = 0; it < 8; it++) {
            int c = tid + it * 256;
            int row = c >> 4, k8 = c & 15;
            uint4 v = *(uint4*)&buf[row][k8 * 8];
            *(uint4*)&Cb[(size_t)(m0 + row) * N + n0 + k8 * 8] = v;
        }
    }
}

// ---------------- flash attention (causal), paired Q-tiles ------------------
// ROUND-7 CONFIG (verbatim revert). 256 blocks x 512 threads; block p handles
// qt=15-p then qt=p (34 k-iterations each, perfectly balanced); 8 waves x 16
// q-rows = 128-row Q-tile. S^T trick keeps P in registers. Q pre-scaled by
// 0.125*log2e in gemm1. LESSON (round 8): splitting into 2x 256-thread
// blocks/CU regressed 5x — keep one fat block per CU here.
__global__ __launch_bounds__(512) void attn_kernel(const u16* __restrict__ qkv,
                                                   const u16* __restrict__ VT,
                                                   u16* __restrict__ out) {
    const int S = 2048, D = 1024, stride = 3072;
    int idx = blockIdx.x;                 // 256 blocks
    int p = idx >> 5, bh = idx & 31;
    int qtb[2] = {15 - p, p};             // phase 0 large, phase 1 small
    int b = bh >> 4, h = bh & 15;
    int tid = threadIdx.x;
    int wave = tid >> 6, lane = tid & 63;
    int quad = lane >> 4, l16 = lane & 15;

    __shared__ u16 Klds[2][64 * 64];      // slot (r,cc) holds chunk (r, cc^(r&7))
    __shared__ u16 Vlds[2][64 * 64];
    __shared__ u16 Obuf[8][16][72];       // per-wave output repack

    const u16* Qp = qkv + (size_t)(b * S) * stride + h * 64;
    const u16* Kp = Qp + D;
    const u16* Vtp = VT + (size_t)bh * 64 * S;

    short8 qf[2][2];                      // [phase][k-half]
    for (int ph = 0; ph < 2; ph++) {
        int qrow = qtb[ph] * 128 + wave * 16 + l16;
        qf[ph][0] = *(const short8*)&Qp[(size_t)qrow * stride + quad * 8];
        qf[ph][1] = *(const short8*)&Qp[(size_t)qrow * stride + 32 + quad * 8];
    }

    int nt0 = 2 * qtb[0] + 2;
    int total = nt0 + 2 * qtb[1] + 2;     // always 34

    auto stage = [&](int kt, int bsel) {
        int c = tid;                      // 512 chunks of 16B each for K and V
        int r = c >> 3, cc = c & 7;
        int gsrc = (cc ^ (r & 7)) * 8;
        glds16(&Kp[(size_t)(kt * 64 + r) * stride + gsrc], &Klds[bsel][c * 8]);
        glds16(&Vtp[(size_t)r * S + kt * 64 + gsrc], &Vlds[bsel][c * 8]);
    };

    stage(0, 0);

    f32x4 O[4] = {};
    float lsum = 0.f;

    for (int it = 0; it < total; it++) {
        int ph = (it >= nt0) ? 1 : 0;
        int kt = ph ? it - nt0 : it;
        int qt = qtb[ph];
        int cur = it & 1;
        __syncthreads();                  // drains DMA for this tile
        if (it + 1 < total) {
            int it2 = it + 1;
            int k2 = (it2 >= nt0) ? it2 - nt0 : it2;
            stage(k2, cur ^ 1);
        }

        // K fragments (A-operand): rows = seq
        short8 kf[4][2];
        for (int nb = 0; nb < 4; nb++) {
            int r = nb * 16 + l16;
            kf[nb][0] = *(short8*)&Klds[cur][r * 64 + ((0 + quad) ^ (r & 7)) * 8];
            kf[nb][1] = *(short8*)&Klds[cur][r * 64 + ((4 + quad) ^ (r & 7)) * 8];
        }
        // S^T[k][q]: lane q=l16, k=nb*16+quad*4+r (pre-scaled Q)
        f32x4 st[4];
        for (int nb = 0; nb < 4; nb++) {
            f32x4 t = {};
            t = __builtin_amdgcn_mfma_f32_16x16x32_bf16(kf[nb][0], qf[ph][0], t, 0, 0, 0);
            t = __builtin_amdgcn_mfma_f32_16x16x32_bf16(kf[nb][1], qf[ph][1], t, 0, 0, 0);
            st[nb] = t;
        }

        if (kt >= 2 * qt) {               // causal boundary tiles
            int qabs = qt * 128 + wave * 16 + l16;
            for (int nb = 0; nb < 4; nb++) {
                int kb = kt * 64 + nb * 16 + quad * 4;
                for (int r = 0; r < 4; r++) {
                    float e = __builtin_amdgcn_exp2f(st[nb][r]);
                    st[nb][r] = (kb + r <= qabs) ? e : 0.f;
                }
            }
        } else {
            for (int nb = 0; nb < 4; nb++)
                for (int r = 0; r < 4; r++)
                    st[nb][r] = __builtin_amdgcn_exp2f(st[nb][r]);
        }

        // partial row sums + pack P to bf16 A-frags (v_perm, round-half-up)
        s16x4 pf[4];
        for (int nb = 0; nb < 4; nb++) {
            lsum += (st[nb][0] + st[nb][1]) + (st[nb][2] + st[nb][3]);
            uint2 pk;
            pk.x = pkbf(st[nb][1], st[nb][0]);
            pk.y = pkbf(st[nb][3], st[nb][2]);
            pf[nb] = __builtin_bit_cast(s16x4, pk);
        }

        // O[q][d] += P @ V via 16x16x16 (k=16 seq chunks)
        for (int db = 0; db < 4; db++) {
            int rr = db * 16 + l16;
            for (int kc = 0; kc < 4; kc++) {
                int g = kc * 2 + (quad >> 1);
                int slot = g ^ (rr & 7);
                s16x4 vf = *(s16x4*)&Vlds[cur][rr * 64 + slot * 8 + (quad & 1) * 4];
                O[db] = __builtin_amdgcn_mfma_f32_16x16x16bf16_1k(
                    pf[kc], vf, O[db], 0, 0, 0);
            }
        }

        // phase epilogue (after the phase's last tile)
        if (it == nt0 - 1 || it == total - 1) {
            float v = lsum;
            v += __shfl_xor(v, 16);
            v += __shfl_xor(v, 32);       // full row sum at lane q=l16
            float rinv[4];
            for (int r = 0; r < 4; r++)
                rinv[r] = 1.f / __shfl(v, (lane & 48) | (quad * 4 + r));
            for (int db = 0; db < 4; db++)
                for (int r = 0; r < 4; r++)
                    Obuf[wave][quad * 4 + r][db * 16 + l16] =
                        f2bf(O[db][r] * rinv[r]);
            __asm__ volatile("s_waitcnt lgkmcnt(0)" ::: "memory");
            for (int i = 0; i < 2; i++) {
                int c = i * 64 + lane;
                int row = c >> 3, cc = c & 7;
                uint4 vv = *(uint4*)&Obuf[wave][row][cc * 8];
                int grow = qt * 128 + wave * 16 + row;
                *(uint4*)&out[(size_t)(b * S + grow) * D + h * 64 + cc * 8] = vv;
            }
            for (int db = 0; db < 4; db++) O[db] = (f32x4){0.f, 0.f, 0.f, 0.f};
            lsum = 0.f;
        }
    }
}

// ---------------------------------------------------------------------------
extern "C" void kernel_launch(void* const* d_in, const int* in_sizes, int n_in,
                              void* d_out, int out_size, void* d_ws, size_t ws_size,
                              hipStream_t stream) {
    const float* x     = (const float*)d_in[0];
    const float* w_in  = (const float*)d_in[1];
    const float* b_in  = (const float*)d_in[2];
    const float* w_out = (const float*)d_in[3];
    const float* b_out = (const float*)d_in[4];

    const int Bsz = 2, S = 2048, D = 1024, H = 16;
    const int M = Bsz * S;
    const int N1 = 3 * D;
    const float sc = 0.125f * 1.44269504f;  // 1/sqrt(64) * log2(e)

    u16* ws    = (u16*)d_ws;
    u16* Xb    = ws;
    u16* WtIn  = Xb + (size_t)M * D;
    u16* WtOut = WtIn + (size_t)N1 * D;
    u16* qkvb  = WtOut + (size_t)D * D;
    u16* attnb = qkvb + (size_t)M * N1;
    // Vt lives in d_out (16 MB, needs 8 MB): fully overwritten by gemm2 later.
    u16* Vt    = (u16*)d_out;

    prep<<<8192, 256, 0, stream>>>(x, w_in, w_out, Xb, WtIn, WtOut);
    gemm_bt<<<(M / BM) * (N1 / BN), 256, 0, stream>>>(Xb, WtIn, b_in, qkvb,
                                                      M, N1, D, 0, D, sc, Vt);
    attn_kernel<<<256, 512, 0, stream>>>(qkvb, Vt, attnb);
    gemm_bt<<<(M / BM) * (D / BN), 256, 0, stream>>>(attnb, WtOut, b_out, d_out,
                                                     M, D, D, 1, 0, 1.f, nullptr);
}

// Round 10
// 185.346 us; speedup vs baseline: 2.1294x; 1.1242x over previous
//
#include <hip/hip_runtime.h>
#include <hip/hip_bf16.h>

typedef __attribute__((ext_vector_type(8))) short short8;
typedef __attribute__((ext_vector_type(4))) short s16x4;
typedef __attribute__((ext_vector_type(4))) float f32x4;
typedef unsigned short u16;

// round-to-nearest-even fp32 -> bf16
__device__ inline u16 f2bf(float f) {
    union { float f; unsigned u; } x{f};
    unsigned r = (x.u + 0x7fff + ((x.u >> 16) & 1)) >> 16;
    return (u16)r;
}

// pack two fp32 -> packed bf16 pair (round-half-up via +0x8000, then v_perm)
__device__ inline unsigned pkbf(float hi, float lo) {
    unsigned a = __builtin_bit_cast(unsigned, hi) + 0x8000u;
    unsigned b = __builtin_bit_cast(unsigned, lo) + 0x8000u;
    return __builtin_amdgcn_perm(a, b, 0x07060302u);
}

// async 16B global -> LDS (wave-uniform base + lane*16 layout)
__device__ inline void glds16(const u16* g, u16* l) {
    __builtin_amdgcn_global_load_lds(
        (const __attribute__((address_space(1))) void*)g,
        (__attribute__((address_space(3))) void*)l, 16, 0, 0);
}

// ---------------- fused prep: cvt x -> bf16 | transpose w_in | w_out --------
__global__ __launch_bounds__(256) void prep(const float* __restrict__ x,
                                            const float* __restrict__ w_in,
                                            const float* __restrict__ w_out,
                                            u16* __restrict__ Xb,
                                            u16* __restrict__ WtIn,
                                            u16* __restrict__ WtOut) {
    __shared__ float tile[32][33];
    int bx = blockIdx.x, tid = threadIdx.x;
    if (bx < 4096) {
        int i = (bx * 256 + tid) * 4;
        float4 v = *(const float4*)&x[i];
        uint2 o;
        o.x = (unsigned)f2bf(v.x) | ((unsigned)f2bf(v.y) << 16);
        o.y = (unsigned)f2bf(v.z) | ((unsigned)f2bf(v.w) << 16);
        *(uint2*)&Xb[i] = o;
        return;
    }
    const float* W; u16* Wt; int K, N, n0, k0;
    if (bx < 7168) {
        int b2 = bx - 4096;                 // w_in: K=1024, N=3072
        W = w_in; Wt = WtIn; K = 1024; N = 3072;
        n0 = (b2 % 96) * 32; k0 = (b2 / 96) * 32;
    } else {
        int b3 = bx - 7168;                 // w_out: K=1024, N=1024
        W = w_out; Wt = WtOut; K = 1024; N = 1024;
        n0 = (b3 & 31) * 32; k0 = (b3 >> 5) * 32;
    }
    int tx = tid & 31, ty = tid >> 5;
    for (int i = 0; i < 32; i += 8)
        tile[ty + i][tx] = W[(size_t)(k0 + ty + i) * N + n0 + tx];
    __syncthreads();
    for (int i = 0; i < 32; i += 8)
        Wt[(size_t)(n0 + ty + i) * K + k0 + tx] = f2bf(tile[tx][ty + i]);
}

// ---------------- transpose V slice of qkv -> Vt[b,h,dh,S] bf16 -------------
__global__ __launch_bounds__(256) void transpose_v(const u16* __restrict__ qkv,
                                                   u16* __restrict__ VT) {
    __shared__ u16 t[32][33];
    int s0 = blockIdx.x * 32, d0 = blockIdx.y * 32, bh = blockIdx.z;
    int b = bh >> 4, h = bh & 15;
    int tx = threadIdx.x, ty = threadIdx.y; // block (32,8)
    const u16* Vp = qkv + (size_t)(b * 2048) * 3072 + 2048 + h * 64;
    for (int i = 0; i < 32; i += 8)
        t[ty + i][tx] = Vp[(size_t)(s0 + ty + i) * 3072 + d0 + tx];
    __syncthreads();
    u16* Vr = VT + (size_t)bh * 64 * 2048;
    for (int i = 0; i < 32; i += 8)
        Vr[(size_t)(d0 + ty + i) * 2048 + s0 + tx] = t[tx][ty + i];
}

// ---------------- GEMM: C[M][N] = A[M][K] @ Bt[N][K]^T + bias ---------------
#define BM 128
#define BN 128
#define BK 64
__global__ __launch_bounds__(256) void gemm_bt(const u16* __restrict__ A,
                                               const u16* __restrict__ Bt,
                                               const float* __restrict__ bias,
                                               void* __restrict__ C,
                                               int M, int N, int K, int c_is_f32,
                                               int qcols, float qscale) {
    __shared__ u16 smem[2 * BM * BK + 2048];
    u16* As = smem;
    u16* Bs = smem + BM * BK;

    int tid = threadIdx.x;
    int wave = tid >> 6, lane = tid & 63;
    int quad = lane >> 4, l16 = lane & 15;
    int wm = (wave >> 1) * 64, wn = (wave & 1) * 64;

    int nm = M / BM, nn = N / BN;
    const int GM = 8;
    int per_group = GM * nn;
    int group = blockIdx.x / per_group;
    int rem = blockIdx.x % per_group;
    int first_m = group * GM;
    int gsz = (nm - first_m < GM) ? (nm - first_m) : GM;
    int m0 = (first_m + rem % gsz) * BM;
    int n0 = (rem / gsz) * BN;

    f32x4 acc[4][4] = {};

    for (int k0 = 0; k0 < K; k0 += BK) {
        __syncthreads();
        for (int i = 0; i < 4; i++) {
            int c = tid + i * 256;
            int r = c >> 3, cc = c & 7;
            int gsrc = (cc ^ (r & 7)) * 8;          // XOR swizzle
            glds16(&A[(size_t)(m0 + r) * K + k0 + gsrc], As + c * 8);
            glds16(&Bt[(size_t)(n0 + r) * K + k0 + gsrc], Bs + c * 8);
        }
        __syncthreads();
        for (int ks = 0; ks < 2; ks++) {
            short8 af[4], bf[4];
            for (int i = 0; i < 4; i++) {
                int row = wm + i * 16 + l16;
                int slot = (ks * 4 + quad) ^ (row & 7);
                af[i] = *(short8*)&As[row * BK + slot * 8];
            }
            for (int j = 0; j < 4; j++) {
                int row = wn + j * 16 + l16;
                int slot = (ks * 4 + quad) ^ (row & 7);
                bf[j] = *(short8*)&Bs[row * BK + slot * 8];
            }
            for (int i = 0; i < 4; i++)
                for (int j = 0; j < 4; j++)
                    acc[i][j] = __builtin_amdgcn_mfma_f32_16x16x32_bf16(
                        af[i], bf[j], acc[i][j], 0, 0, 0);
        }
    }

    if (c_is_f32) {
        for (int i = 0; i < 4; i++)
            for (int j = 0; j < 4; j++) {
                int col = n0 + wn + j * 16 + l16;
                float bv = bias ? bias[col] : 0.f;
                for (int r = 0; r < 4; r++) {
                    int row = m0 + wm + i * 16 + quad * 4 + r;
                    ((float*)C)[(size_t)row * N + col] = acc[i][j][r] + bv;
                }
            }
    } else {
        __syncthreads();
        u16 (*buf)[136] = (u16(*)[136])smem;
        for (int i = 0; i < 4; i++)
            for (int j = 0; j < 4; j++) {
                int col = wn + j * 16 + l16;
                float bv = bias ? bias[n0 + col] : 0.f;
                float scl = (n0 + col < qcols) ? qscale : 1.f;
                for (int r = 0; r < 4; r++)
                    buf[wm + i * 16 + quad * 4 + r][col] =
                        f2bf((acc[i][j][r] + bv) * scl);
            }
        __syncthreads();
        u16* Cb = (u16*)C;
        for (int it = 0; it < 8; it++) {
            int c = tid + it * 256;
            int row = c >> 4, k8 = c & 15;
            uint4 v = *(uint4*)&buf[row][k8 * 8];
            *(uint4*)&Cb[(size_t)(m0 + row) * N + n0 + k8 * 8] = v;
        }
    }
}

// ---------------- flash attention (causal), dual-chain paired tiles ---------
// 256 blocks x 512 threads (round-7 shape: one fat block/CU, 8 waves x 16 q).
// Block p: qt=15-p then qt=p. Each phase has an EVEN tile count, processed as
// pairs (kt=2j, 2j+1) with two independent accumulator chains A/B — valid
// because no-max softmax makes tile contributions order-independent sums.
// Two chains give the scheduler independent MFMA/VALU/LDS dataflow to overlap
// (round-7 single chain ran the pipes serialized). 17 pairs per block, exact
// balance. LESSON (round 8): do NOT split into 2 blocks/CU.
__global__ __launch_bounds__(512, 2) void attn_kernel(const u16* __restrict__ qkv,
                                                      const u16* __restrict__ VT,
                                                      u16* __restrict__ out) {
    const int S = 2048, D = 1024, stride = 3072;
    int idx = blockIdx.x;                 // 256 blocks
    int p = idx >> 5, bh = idx & 31;
    int qtb[2] = {15 - p, p};             // phase 0 large, phase 1 small
    int b = bh >> 4, h = bh & 15;
    int tid = threadIdx.x;
    int wave = tid >> 6, lane = tid & 63;
    int quad = lane >> 4, l16 = lane & 15;

    __shared__ u16 Klds[2][2][64 * 64];   // [dbuf][chain]; XOR-swizzled rows
    __shared__ u16 Vlds[2][2][64 * 64];
    __shared__ u16 Obuf[8][16][72];       // per-wave output repack

    const u16* Qp = qkv + (size_t)(b * S) * stride + h * 64;
    const u16* Kp = Qp + D;
    const u16* Vtp = VT + (size_t)bh * 64 * S;

    short8 qf[2][2];                      // [phase][k-half]
    for (int ph = 0; ph < 2; ph++) {
        int qrow = qtb[ph] * 128 + wave * 16 + l16;
        qf[ph][0] = *(const short8*)&Qp[(size_t)qrow * stride + quad * 8];
        qf[ph][1] = *(const short8*)&Qp[(size_t)qrow * stride + 32 + quad * 8];
    }

    int np0 = qtb[0] + 1;                 // pairs in phase 0
    int ntp = np0 + qtb[1] + 1;           // always 17

    auto stage = [&](int kt, int bsel, int ch) {
        int c = tid;                      // 512 chunks of 16B each for K and V
        int r = c >> 3, cc = c & 7;
        int gsrc = (cc ^ (r & 7)) * 8;
        glds16(&Kp[(size_t)(kt * 64 + r) * stride + gsrc], &Klds[bsel][ch][c * 8]);
        glds16(&Vtp[(size_t)r * S + kt * 64 + gsrc], &Vlds[bsel][ch][c * 8]);
    };

    stage(0, 0, 0);
    stage(1, 0, 1);

    f32x4 Oa[4] = {}, Ob[4] = {};
    float lsa = 0.f, lsb = 0.f;

    for (int jp = 0; jp < ntp; jp++) {
        int ph = (jp >= np0) ? 1 : 0;
        int j = ph ? jp - np0 : jp;
        int qt = qtb[ph];
        int ka = 2 * j, kb = 2 * j + 1;
        int cur = jp & 1;
        __syncthreads();                  // drains DMA for this pair
        if (jp + 1 < ntp) {
            int jp2 = jp + 1;
            int j2 = (jp2 >= np0) ? jp2 - np0 : jp2;
            stage(2 * j2, cur ^ 1, 0);
            stage(2 * j2 + 1, cur ^ 1, 1);
        }

        // K fragments for both chains (A-operand): rows = seq
        short8 kfa[4][2], kfb[4][2];
        for (int nb = 0; nb < 4; nb++) {
            int r = nb * 16 + l16;
            int s0 = ((0 + quad) ^ (r & 7)) * 8;
            int s1 = ((4 + quad) ^ (r & 7)) * 8;
            kfa[nb][0] = *(short8*)&Klds[cur][0][r * 64 + s0];
            kfa[nb][1] = *(short8*)&Klds[cur][0][r * 64 + s1];
            kfb[nb][0] = *(short8*)&Klds[cur][1][r * 64 + s0];
            kfb[nb][1] = *(short8*)&Klds[cur][1][r * 64 + s1];
        }
        // S^T per chain: lane q=l16, k=nb*16+quad*4+r (Q pre-scaled)
        f32x4 sta[4], stb[4];
        for (int nb = 0; nb < 4; nb++) {
            f32x4 t = {};
            t = __builtin_amdgcn_mfma_f32_16x16x32_bf16(kfa[nb][0], qf[ph][0], t, 0, 0, 0);
            t = __builtin_amdgcn_mfma_f32_16x16x32_bf16(kfa[nb][1], qf[ph][1], t, 0, 0, 0);
            sta[nb] = t;
            f32x4 u = {};
            u = __builtin_amdgcn_mfma_f32_16x16x32_bf16(kfb[nb][0], qf[ph][0], u, 0, 0, 0);
            u = __builtin_amdgcn_mfma_f32_16x16x32_bf16(kfb[nb][1], qf[ph][1], u, 0, 0, 0);
            stb[nb] = u;
        }

        if (j == qt) {                    // last pair of phase: both boundary
            int qabs = qt * 128 + wave * 16 + l16;
            for (int nb = 0; nb < 4; nb++) {
                int kba = ka * 64 + nb * 16 + quad * 4;
                int kbb = kb * 64 + nb * 16 + quad * 4;
                for (int r = 0; r < 4; r++) {
                    float ea = __builtin_amdgcn_exp2f(sta[nb][r]);
                    sta[nb][r] = (kba + r <= qabs) ? ea : 0.f;
                    float eb = __builtin_amdgcn_exp2f(stb[nb][r]);
                    stb[nb][r] = (kbb + r <= qabs) ? eb : 0.f;
                }
            }
        } else {
            for (int nb = 0; nb < 4; nb++)
                for (int r = 0; r < 4; r++) {
                    sta[nb][r] = __builtin_amdgcn_exp2f(sta[nb][r]);
                    stb[nb][r] = __builtin_amdgcn_exp2f(stb[nb][r]);
                }
        }

        // partial sums + pack P per chain (v_perm, round-half-up)
        s16x4 pfa[4], pfb[4];
        for (int nb = 0; nb < 4; nb++) {
            lsa += (sta[nb][0] + sta[nb][1]) + (sta[nb][2] + sta[nb][3]);
            lsb += (stb[nb][0] + stb[nb][1]) + (stb[nb][2] + stb[nb][3]);
            uint2 pk;
            pk.x = pkbf(sta[nb][1], sta[nb][0]);
            pk.y = pkbf(sta[nb][3], sta[nb][2]);
            pfa[nb] = __builtin_bit_cast(s16x4, pk);
            pk.x = pkbf(stb[nb][1], stb[nb][0]);
            pk.y = pkbf(stb[nb][3], stb[nb][2]);
            pfb[nb] = __builtin_bit_cast(s16x4, pk);
        }

        // PV per chain via 16x16x16 (k=16 seq chunks)
        for (int db = 0; db < 4; db++) {
            int rr = db * 16 + l16;
            for (int kc = 0; kc < 4; kc++) {
                int g = kc * 2 + (quad >> 1);
                int slot = g ^ (rr & 7);
                int off = rr * 64 + slot * 8 + (quad & 1) * 4;
                s16x4 vfa = *(s16x4*)&Vlds[cur][0][off];
                Oa[db] = __builtin_amdgcn_mfma_f32_16x16x16bf16_1k(
                    pfa[kc], vfa, Oa[db], 0, 0, 0);
                s16x4 vfb = *(s16x4*)&Vlds[cur][1][off];
                Ob[db] = __builtin_amdgcn_mfma_f32_16x16x16bf16_1k(
                    pfb[kc], vfb, Ob[db], 0, 0, 0);
            }
        }

        // phase epilogue (after the phase's last pair)
        if (jp == np0 - 1 || jp == ntp - 1) {
            float v = lsa + lsb;
            v += __shfl_xor(v, 16);
            v += __shfl_xor(v, 32);       // full row sum at lane q=l16
            float rinv[4];
            for (int r = 0; r < 4; r++)
                rinv[r] = 1.f / __shfl(v, (lane & 48) | (quad * 4 + r));
            for (int db = 0; db < 4; db++)
                for (int r = 0; r < 4; r++)
                    Obuf[wave][quad * 4 + r][db * 16 + l16] =
                        f2bf((Oa[db][r] + Ob[db][r]) * rinv[r]);
            __asm__ volatile("s_waitcnt lgkmcnt(0)" ::: "memory");
            for (int i = 0; i < 2; i++) {
                int c = i * 64 + lane;
                int row = c >> 3, cc = c & 7;
                uint4 vv = *(uint4*)&Obuf[wave][row][cc * 8];
                int grow = qt * 128 + wave * 16 + row;
                *(uint4*)&out[(size_t)(b * S + grow) * D + h * 64 + cc * 8] = vv;
            }
            for (int db = 0; db < 4; db++) {
                Oa[db] = (f32x4){0.f, 0.f, 0.f, 0.f};
                Ob[db] = (f32x4){0.f, 0.f, 0.f, 0.f};
            }
            lsa = 0.f;
            lsb = 0.f;
        }
    }
}

// ---------------------------------------------------------------------------
extern "C" void kernel_launch(void* const* d_in, const int* in_sizes, int n_in,
                              void* d_out, int out_size, void* d_ws, size_t ws_size,
                              hipStream_t stream) {
    const float* x     = (const float*)d_in[0];
    const float* w_in  = (const float*)d_in[1];
    const float* b_in  = (const float*)d_in[2];
    const float* w_out = (const float*)d_in[3];
    const float* b_out = (const float*)d_in[4];

    const int Bsz = 2, S = 2048, D = 1024, H = 16;
    const int M = Bsz * S;
    const int N1 = 3 * D;
    const float sc = 0.125f * 1.44269504f;  // 1/sqrt(64) * log2(e)

    u16* ws    = (u16*)d_ws;
    u16* Xb    = ws;
    u16* WtIn  = Xb + (size_t)M * D;
    u16* WtOut = WtIn + (size_t)N1 * D;
    u16* qkvb  = WtOut + (size_t)D * D;
    u16* attnb = qkvb + (size_t)M * N1;
    u16* Vt    = Xb;                       // alias: Xb dead once gemm1 ran

    prep<<<8192, 256, 0, stream>>>(x, w_in, w_out, Xb, WtIn, WtOut);
    gemm_bt<<<(M / BM) * (N1 / BN), 256, 0, stream>>>(Xb, WtIn, b_in, qkvb,
                                                      M, N1, D, 0, D, sc);
    transpose_v<<<dim3(S / 32, 2, Bsz * H), dim3(32, 8), 0, stream>>>(qkvb, Vt);
    attn_kernel<<<256, 512, 0, stream>>>(qkvb, Vt, attnb);
    gemm_bt<<<(M / BM) * (D / BN), 256, 0, stream>>>(attnb, WtOut, b_out, d_out,
                                                     M, D, D, 1, 0, 1.f);
}